// Round 1
// baseline (21187.137 us; speedup 1.0000x reference)
//
#include <hip/hip_runtime.h>
#include <cstdint>
#include <cstddef>

// ---------------- types / helpers ----------------
typedef __attribute__((ext_vector_type(8))) short bf16x8;   // 8 bf16 in 4 VGPRs
typedef __attribute__((ext_vector_type(4))) float f32x4;
typedef __attribute__((ext_vector_type(4))) float float4v;
typedef __attribute__((ext_vector_type(4))) unsigned short ushort4v;
typedef unsigned short u16;
typedef unsigned int u32;

#define DEVFN static __device__ __forceinline__

DEVFN u16 f2bf(float f) {               // fp32 -> bf16 round-to-nearest-even
  u32 u = __float_as_uint(f);
  return (u16)((u + 0x7fffu + ((u >> 16) & 1u)) >> 16);
}
DEVFN float bf2f(u16 h) { return __uint_as_float(((u32)h) << 16); }
DEVFN float sigmf(float x) { return 1.f / (1.f + __expf(-x)); }
DEVFN float tanhf_fast(float x) {       // saturation-safe tanh
  float e = __expf(-2.f * fabsf(x));
  float t = (1.f - e) / (1.f + e);
  return x >= 0.f ? t : -t;
}

// dims: L=8 N=64 T=128 D=1024 H=1024 ; TL = 1024 steps ; 3H = 3072
// ws layout (bytes):
//   [0,4096)        barrier counters (4 groups x 256B)
//   [4096, +256KB)  h bf16 double buffer [2][64][1024]
//   then W_ih bf16 (6291456), W_hh bf16 (6291456), gi bf16 (65536 x 3072)
static constexpr size_t WS_BAR  = 0;
static constexpr size_t WS_HBUF = 4096;
static constexpr size_t WS_WIH  = WS_HBUF + 262144;
static constexpr size_t WS_WHH  = WS_WIH + 6291456;
static constexpr size_t WS_GI   = WS_WHH + 6291456;
static constexpr size_t WS_END  = WS_GI + (size_t)65536 * 3072 * 2;  // ~396 MiB

// ---------------- fp32 -> bf16 convert (4 elems/thread, exact grid) ----------------
__global__ void cvt4_kernel(const float* __restrict__ src, u16* __restrict__ dst, int n4) {
  int i = blockIdx.x * blockDim.x + threadIdx.x;
  if (i >= n4) return;
  float4v v = ((const float4v*)src)[i];
  ushort4v o;
  o[0] = f2bf(v[0]); o[1] = f2bf(v[1]); o[2] = f2bf(v[2]); o[3] = f2bf(v[3]);
  ((ushort4v*)dst)[i] = o;
}

// ---------------- phase A: gi[t'*64+n][g] = sum_d x[t',n,d] * W_ih[g,d] ----------------
// 128 (rows) x 128 (g) tile, BK=32, 4 waves, reg-staged fp32->bf16, XOR-swizzled LDS.
__launch_bounds__(256, 2)
__global__ void gemm_gi_kernel(const float* __restrict__ x, const u16* __restrict__ wih,
                               u16* __restrict__ gi) {
  const int tid = threadIdx.x;
  const int lane = tid & 63;
  const int wv = tid >> 6;
  const int bid = blockIdx.x;
  const int gt = bid % 24;   // g tile
  const int rt = bid / 24;   // row tile (512)

  __shared__ __align__(16) u16 Ash[128 * 32];
  __shared__ __align__(16) u16 Bsh[128 * 32];

  // staging: thread -> (row ra, k-half ch)
  const int ra = tid >> 1;
  const int ch = (tid & 1) * 16;
  const int r  = rt * 128 + ra;          // flattened row = t'*64 + n
  const int tp = r >> 6, n = r & 63;
  const int ll = tp & 7, tt = tp >> 3;   // t' = t*8 + l
  const float* arow = x + ((size_t)((ll * 64 + n) * 128 + tt)) * 1024 + ch;
  const u16*   brow = wih + ((size_t)(gt * 128 + ra)) * 1024 + ch;
  const int wbyte0 = ra * 64 + ch * 2;
  const int wswz   = (ra & 7) << 4;

  const int rw = (wv >> 1) * 64;     // wave row block
  const int cw = (wv & 1) * 64;      // wave col block
  const int kb = (lane >> 4) * 16;   // k byte offset within 64B row

  f32x4 acc[4][4];
#pragma unroll
  for (int i = 0; i < 4; ++i)
#pragma unroll
    for (int j = 0; j < 4; ++j) acc[i][j] = (f32x4){0.f, 0.f, 0.f, 0.f};

  for (int kt = 0; kt < 32; ++kt) {
    // stage A (fp32 -> bf16) and B (bf16)
    float4v a0 = *(const float4v*)(arow + kt * 32 + 0);
    float4v a1 = *(const float4v*)(arow + kt * 32 + 4);
    float4v a2 = *(const float4v*)(arow + kt * 32 + 8);
    float4v a3 = *(const float4v*)(arow + kt * 32 + 12);
    bf16x8 b0 = *(const bf16x8*)(brow + kt * 32 + 0);
    bf16x8 b1 = *(const bf16x8*)(brow + kt * 32 + 8);
    union { u16 u[8]; bf16x8 v; } p0, p1;
    p0.u[0] = f2bf(a0[0]); p0.u[1] = f2bf(a0[1]); p0.u[2] = f2bf(a0[2]); p0.u[3] = f2bf(a0[3]);
    p0.u[4] = f2bf(a1[0]); p0.u[5] = f2bf(a1[1]); p0.u[6] = f2bf(a1[2]); p0.u[7] = f2bf(a1[3]);
    p1.u[0] = f2bf(a2[0]); p1.u[1] = f2bf(a2[1]); p1.u[2] = f2bf(a2[2]); p1.u[3] = f2bf(a2[3]);
    p1.u[4] = f2bf(a3[0]); p1.u[5] = f2bf(a3[1]); p1.u[6] = f2bf(a3[2]); p1.u[7] = f2bf(a3[3]);
    *(bf16x8*)((char*)Ash + ((wbyte0 +  0) ^ wswz)) = p0.v;
    *(bf16x8*)((char*)Ash + ((wbyte0 + 16) ^ wswz)) = p1.v;
    *(bf16x8*)((char*)Bsh + ((wbyte0 +  0) ^ wswz)) = b0;
    *(bf16x8*)((char*)Bsh + ((wbyte0 + 16) ^ wswz)) = b1;
    __syncthreads();

    bf16x8 af[4], bfr[4];
#pragma unroll
    for (int mi = 0; mi < 4; ++mi) {
      int row = rw + mi * 16 + (lane & 15);
      af[mi] = *(const bf16x8*)((char*)Ash + ((row * 64 + kb) ^ ((row & 7) << 4)));
    }
#pragma unroll
    for (int nj = 0; nj < 4; ++nj) {
      int row = cw + nj * 16 + (lane & 15);
      bfr[nj] = *(const bf16x8*)((char*)Bsh + ((row * 64 + kb) ^ ((row & 7) << 4)));
    }
#pragma unroll
    for (int mi = 0; mi < 4; ++mi)
#pragma unroll
      for (int nj = 0; nj < 4; ++nj)
        acc[mi][nj] = __builtin_amdgcn_mfma_f32_16x16x32_bf16(af[mi], bfr[nj], acc[mi][nj], 0, 0, 0);
    __syncthreads();
  }

  const size_t rbase = (size_t)rt * 128;
  const int gbase = gt * 128;
#pragma unroll
  for (int mi = 0; mi < 4; ++mi)
#pragma unroll
    for (int nj = 0; nj < 4; ++nj) {
      int col = gbase + cw + nj * 16 + (lane & 15);
#pragma unroll
      for (int rr = 0; rr < 4; ++rr) {
        int row = rw + mi * 16 + (lane >> 4) * 4 + rr;
        gi[(rbase + row) * 3072 + col] = f2bf(acc[mi][nj][rr]);
      }
    }
}

// ---------------- phase B: persistent GRU scan ----------------
// 256 wgs = 4 batch-groups (16 rows each) x 64 wgs (16 hidden cols each).
// W_hh slice lives in VGPRs (96/lane). K split 4-ways over waves, LDS reduce.
// One group-barrier per step; h broadcast via bf16 double buffer in ws.
__launch_bounds__(256, 2)
__global__ void gru_scan_kernel(const u16* __restrict__ gi, const u16* __restrict__ whh,
                                const float* __restrict__ h0,
                                const float* __restrict__ b_ih, const float* __restrict__ b_hh,
                                u16* __restrict__ hbuf, u32* __restrict__ bar,
                                float* __restrict__ out) {
  const int tid = threadIdx.x, lane = tid & 63, wv = tid >> 6;
  const int b = blockIdx.x;
  const int grp = b >> 6;          // batch rows grp*16 .. +16
  const int j0 = (b & 63) * 16;    // hidden cols j0 .. j0+16

  __shared__ __align__(16) float part[4 * 3 * 16 * 16];  // [wave][gate][col][row]

  // W_hh fragments in registers: wave wv owns k in [wv*256, wv*256+256)
  bf16x8 wreg[3][8];
#pragma unroll
  for (int c = 0; c < 3; ++c) {
    const u16* wp = whh + (size_t)(c * 1024 + j0 + (lane & 15)) * 1024
                        + wv * 256 + (lane >> 4) * 8;
#pragma unroll
    for (int kk = 0; kk < 8; ++kk) wreg[c][kk] = *(const bf16x8*)(wp + kk * 32);
  }

  // elementwise assignment: thread -> (row erow, col ej)
  const int erow = tid >> 4, ej = tid & 15;
  const int en = grp * 16 + erow;
  const int gcol = j0 + ej;
  const float bihr = b_ih[gcol], bihz = b_ih[1024 + gcol], bihn = b_ih[2048 + gcol];
  const float bhhr = b_hh[gcol], bhhz = b_hh[1024 + gcol], bhhn = b_hh[2048 + gcol];
  float hcur = h0[(size_t)en * 1024 + gcol];   // fp32 hidden state, register-resident

  u32* cnt = bar + grp * 64;                    // 256B-spaced per-group counter
  const int aoff = (grp * 16 + (lane & 15)) * 1024 + wv * 256 + (lane >> 4) * 8;

  for (int s = 0; s < 1024; ++s) {
    const u16* hb  = hbuf + (size_t)(s & 1) * 65536;
    u16*       hbn = hbuf + (size_t)((s + 1) & 1) * 65536;

    // gi loads (independent of h, issued early)
    size_t gib = ((size_t)(s * 64 + en)) * 3072 + gcol;
    float gir = bf2f(gi[gib]);
    float giz = bf2f(gi[gib + 1024]);
    float gin = bf2f(gi[gib + 2048]);

    // A fragments: h rows of this group, this wave's K quarter
    const u16* hp = hb + aoff;
    bf16x8 af[8];
#pragma unroll
    for (int kk = 0; kk < 8; ++kk) af[kk] = *(const bf16x8*)(hp + kk * 32);

    f32x4 acc[3];
    acc[0] = (f32x4){0,0,0,0}; acc[1] = acc[0]; acc[2] = acc[0];
#pragma unroll
    for (int kk = 0; kk < 8; ++kk) {
      acc[0] = __builtin_amdgcn_mfma_f32_16x16x32_bf16(af[kk], wreg[0][kk], acc[0], 0, 0, 0);
      acc[1] = __builtin_amdgcn_mfma_f32_16x16x32_bf16(af[kk], wreg[1][kk], acc[1], 0, 0, 0);
      acc[2] = __builtin_amdgcn_mfma_f32_16x16x32_bf16(af[kk], wreg[2][kk], acc[2], 0, 0, 0);
    }
#pragma unroll
    for (int c = 0; c < 3; ++c)
      *(f32x4*)&part[(((wv * 3 + c) * 16 + (lane & 15)) * 16 + (lane >> 4) * 4)] = acc[c];
    __syncthreads();

    // K-split reduction + gates (one (row,col) per thread)
    float ghr = 0.f, ghz = 0.f, ghn = 0.f;
#pragma unroll
    for (int ww = 0; ww < 4; ++ww) {
      ghr += part[((ww * 3 + 0) * 16 + ej) * 16 + erow];
      ghz += part[((ww * 3 + 1) * 16 + ej) * 16 + erow];
      ghn += part[((ww * 3 + 2) * 16 + ej) * 16 + erow];
    }
    float rg = sigmf(gir + bihr + ghr + bhhr);
    float zg = sigmf(giz + bihz + ghz + bhhz);
    float ng = tanhf_fast(gin + bihn + rg * (ghn + bhhn));
    float hn = (1.f - zg) * ng + zg * hcur;
    hcur = hn;

    __builtin_nontemporal_store(hn, &out[(size_t)en * 1048576 + (size_t)s * 1024 + gcol]);
    hbn[en * 1024 + gcol] = f2bf(hn);
    if (s == 1023) out[(size_t)67108864 + (size_t)en * 1024 + gcol] = hn;

    // ---- group barrier (device-scope, monotonic counter) ----
    __syncthreads();                 // drains all waves' vmem (stores in L2)
    if (tid == 0) {
      __threadfence();               // release: flush dirty L2 to coherence point
      __hip_atomic_fetch_add(cnt, 1u, __ATOMIC_RELEASE, __HIP_MEMORY_SCOPE_AGENT);
      const u32 tgt = 64u * (u32)(s + 1);
      while (__hip_atomic_load(cnt, __ATOMIC_ACQUIRE, __HIP_MEMORY_SCOPE_AGENT) < tgt)
        __builtin_amdgcn_s_sleep(2);
      __threadfence();               // acquire: invalidate L1/L2
    }
    __syncthreads();
  }
}

// ---------------- launch ----------------
extern "C" void kernel_launch(void* const* d_in, const int* in_sizes, int n_in,
                              void* d_out, int out_size, void* d_ws, size_t ws_size,
                              hipStream_t stream) {
  const float* x     = (const float*)d_in[0];   // (8,64,128,1024)
  const float* h0    = (const float*)d_in[1];   // (1,64,1024)
  const float* wih_f = (const float*)d_in[2];   // (3072,1024)
  const float* whh_f = (const float*)d_in[3];   // (3072,1024)
  const float* bih   = (const float*)d_in[4];   // (3072,)
  const float* bhh   = (const float*)d_in[5];   // (3072,)
  float* out = (float*)d_out;

  if (ws_size < WS_END) return;  // insufficient scratch -> visible failure, no corruption

  char* ws = (char*)d_ws;
  u32* bar   = (u32*)(ws + WS_BAR);
  u16* hbuf  = (u16*)(ws + WS_HBUF);
  u16* wih_b = (u16*)(ws + WS_WIH);
  u16* whh_b = (u16*)(ws + WS_WHH);
  u16* gi    = (u16*)(ws + WS_GI);

  hipMemsetAsync(bar, 0, 4096, stream);  // barrier counters must start at 0 every replay

  cvt4_kernel<<<3072, 256, 0, stream>>>(wih_f, wih_b, 786432);
  cvt4_kernel<<<3072, 256, 0, stream>>>(whh_f, whh_b, 786432);
  cvt4_kernel<<<64,   256, 0, stream>>>(h0, hbuf, 16384);      // h buffer 0 init

  gemm_gi_kernel<<<12288, 256, 0, stream>>>(x, wih_b, gi);

  gru_scan_kernel<<<256, 256, 0, stream>>>(gi, whh_b, h0, bih, bhh, hbuf, bar, out);
}

// Round 2
// 5777.117 us; speedup vs baseline: 3.6674x; 3.6674x over previous
//
#include <hip/hip_runtime.h>
#include <cstdint>
#include <cstddef>

// ---------------- types / helpers ----------------
typedef __attribute__((ext_vector_type(8))) short bf16x8;   // 8 bf16 in 4 VGPRs
typedef __attribute__((ext_vector_type(4))) float f32x4;
typedef __attribute__((ext_vector_type(4))) float float4v;
typedef __attribute__((ext_vector_type(4))) unsigned short ushort4v;
typedef unsigned short u16;
typedef unsigned int u32;

#define DEVFN static __device__ __forceinline__

DEVFN u16 f2bf(float f) {               // fp32 -> bf16 round-to-nearest-even
  u32 u = __float_as_uint(f);
  return (u16)((u + 0x7fffu + ((u >> 16) & 1u)) >> 16);
}
DEVFN float bf2f(u16 h) { return __uint_as_float(((u32)h) << 16); }
DEVFN float sigmf(float x) { return 1.f / (1.f + __expf(-x)); }
DEVFN float tanhf_fast(float x) {       // saturation-safe tanh
  float e = __expf(-2.f * fabsf(x));
  float t = (1.f - e) / (1.f + e);
  return x >= 0.f ? t : -t;
}

// dims: L=8 N=64 T=128 D=1024 H=1024 ; TL = 1024 steps ; 3H = 3072
static constexpr size_t WS_BAR  = 0;
static constexpr size_t WS_HBUF = 4096;
static constexpr size_t WS_WIH  = WS_HBUF + 262144;
static constexpr size_t WS_WHH  = WS_WIH + 6291456;
static constexpr size_t WS_GI   = WS_WHH + 6291456;
static constexpr size_t WS_END  = WS_GI + (size_t)65536 * 3072 * 2;  // ~396 MiB

// ---------------- fp32 -> bf16 convert ----------------
__global__ void cvt4_kernel(const float* __restrict__ src, u16* __restrict__ dst, int n4) {
  int i = blockIdx.x * blockDim.x + threadIdx.x;
  if (i >= n4) return;
  float4v v = ((const float4v*)src)[i];
  ushort4v o;
  o[0] = f2bf(v[0]); o[1] = f2bf(v[1]); o[2] = f2bf(v[2]); o[3] = f2bf(v[3]);
  ((ushort4v*)dst)[i] = o;
}

// ---------------- phase A: gi = xs @ W_ih^T (bf16 out) ----------------
__launch_bounds__(256, 2)
__global__ void gemm_gi_kernel(const float* __restrict__ x, const u16* __restrict__ wih,
                               u16* __restrict__ gi) {
  const int tid = threadIdx.x;
  const int lane = tid & 63;
  const int wv = tid >> 6;
  const int bid = blockIdx.x;
  const int gt = bid % 24;   // g tile
  const int rt = bid / 24;   // row tile (512)

  __shared__ __align__(16) u16 Ash[128 * 32];
  __shared__ __align__(16) u16 Bsh[128 * 32];

  const int ra = tid >> 1;
  const int ch = (tid & 1) * 16;
  const int r  = rt * 128 + ra;          // flattened row = t'*64 + n
  const int tp = r >> 6, n = r & 63;
  const int ll = tp & 7, tt = tp >> 3;   // t' = t*8 + l
  const float* arow = x + ((size_t)((ll * 64 + n) * 128 + tt)) * 1024 + ch;
  const u16*   brow = wih + ((size_t)(gt * 128 + ra)) * 1024 + ch;
  const int wbyte0 = ra * 64 + ch * 2;
  const int wswz   = (ra & 7) << 4;

  const int rw = (wv >> 1) * 64;
  const int cw = (wv & 1) * 64;
  const int kb = (lane >> 4) * 16;

  f32x4 acc[4][4];
#pragma unroll
  for (int i = 0; i < 4; ++i)
#pragma unroll
    for (int j = 0; j < 4; ++j) acc[i][j] = (f32x4){0.f, 0.f, 0.f, 0.f};

  for (int kt = 0; kt < 32; ++kt) {
    float4v a0 = *(const float4v*)(arow + kt * 32 + 0);
    float4v a1 = *(const float4v*)(arow + kt * 32 + 4);
    float4v a2 = *(const float4v*)(arow + kt * 32 + 8);
    float4v a3 = *(const float4v*)(arow + kt * 32 + 12);
    bf16x8 b0 = *(const bf16x8*)(brow + kt * 32 + 0);
    bf16x8 b1 = *(const bf16x8*)(brow + kt * 32 + 8);
    union { u16 u[8]; bf16x8 v; } p0, p1;
    p0.u[0] = f2bf(a0[0]); p0.u[1] = f2bf(a0[1]); p0.u[2] = f2bf(a0[2]); p0.u[3] = f2bf(a0[3]);
    p0.u[4] = f2bf(a1[0]); p0.u[5] = f2bf(a1[1]); p0.u[6] = f2bf(a1[2]); p0.u[7] = f2bf(a1[3]);
    p1.u[0] = f2bf(a2[0]); p1.u[1] = f2bf(a2[1]); p1.u[2] = f2bf(a2[2]); p1.u[3] = f2bf(a2[3]);
    p1.u[4] = f2bf(a3[0]); p1.u[5] = f2bf(a3[1]); p1.u[6] = f2bf(a3[2]); p1.u[7] = f2bf(a3[3]);
    *(bf16x8*)((char*)Ash + ((wbyte0 +  0) ^ wswz)) = p0.v;
    *(bf16x8*)((char*)Ash + ((wbyte0 + 16) ^ wswz)) = p1.v;
    *(bf16x8*)((char*)Bsh + ((wbyte0 +  0) ^ wswz)) = b0;
    *(bf16x8*)((char*)Bsh + ((wbyte0 + 16) ^ wswz)) = b1;
    __syncthreads();

    bf16x8 af[4], bfr[4];
#pragma unroll
    for (int mi = 0; mi < 4; ++mi) {
      int row = rw + mi * 16 + (lane & 15);
      af[mi] = *(const bf16x8*)((char*)Ash + ((row * 64 + kb) ^ ((row & 7) << 4)));
    }
#pragma unroll
    for (int nj = 0; nj < 4; ++nj) {
      int row = cw + nj * 16 + (lane & 15);
      bfr[nj] = *(const bf16x8*)((char*)Bsh + ((row * 64 + kb) ^ ((row & 7) << 4)));
    }
#pragma unroll
    for (int mi = 0; mi < 4; ++mi)
#pragma unroll
      for (int nj = 0; nj < 4; ++nj)
        acc[mi][nj] = __builtin_amdgcn_mfma_f32_16x16x32_bf16(af[mi], bfr[nj], acc[mi][nj], 0, 0, 0);
    __syncthreads();
  }

  const size_t rbase = (size_t)rt * 128;
  const int gbase = gt * 128;
#pragma unroll
  for (int mi = 0; mi < 4; ++mi)
#pragma unroll
    for (int nj = 0; nj < 4; ++nj) {
      int col = gbase + cw + nj * 16 + (lane & 15);
#pragma unroll
      for (int rr = 0; rr < 4; ++rr) {
        int row = rw + mi * 16 + (lane >> 4) * 4 + rr;
        gi[(rbase + row) * 3072 + col] = f2bf(acc[mi][nj][rr]);
      }
    }
}

// ---------------- phase B: persistent GRU scan ----------------
// 256 wgs = 4 batch-groups (16 rows) x 64 wgs (16 hidden cols). W_hh in VGPRs.
// Barrier: relaxed add + relaxed spin + ONE acquire fence (single buffer_inv).
// h broadcast via agent-scope relaxed atomic u32 stores (write-through, no wbl2).
__launch_bounds__(256, 2)
__global__ void gru_scan_kernel(const u16* __restrict__ gi, const u16* __restrict__ whh,
                                const float* __restrict__ h0,
                                const float* __restrict__ b_ih, const float* __restrict__ b_hh,
                                u16* __restrict__ hbuf, u32* __restrict__ bar,
                                float* __restrict__ out) {
  const int tid = threadIdx.x, lane = tid & 63, wv = tid >> 6;
  const int b = blockIdx.x;
  const int grp = b >> 6;          // batch rows grp*16 .. +16
  const int j0 = (b & 63) * 16;    // hidden cols j0 .. j0+16

  // [wave][gate][col][row] fp32, col-stride 17 (coprime 32 -> conflict-free)
  __shared__ float part[4 * 3 * 16 * 17];

  bf16x8 wreg[3][8];
#pragma unroll
  for (int c = 0; c < 3; ++c) {
    const u16* wp = whh + (size_t)(c * 1024 + j0 + (lane & 15)) * 1024
                        + wv * 256 + (lane >> 4) * 8;
#pragma unroll
    for (int kk = 0; kk < 8; ++kk) wreg[c][kk] = *(const bf16x8*)(wp + kk * 32);
  }

  const int erow = tid >> 4, ej = tid & 15;
  const int en = grp * 16 + erow;
  const int gcol = j0 + ej;
  const float bihr = b_ih[gcol], bihz = b_ih[1024 + gcol], bihn = b_ih[2048 + gcol];
  const float bhhr = b_hh[gcol], bhhz = b_hh[1024 + gcol], bhhn = b_hh[2048 + gcol];
  float hcur = h0[(size_t)en * 1024 + gcol];

  u32* cnt = bar + grp * 64;                    // 256B-spaced per-group counter
  const int aoff = (grp * 16 + (lane & 15)) * 1024 + wv * 256 + (lane >> 4) * 8;

  for (int s = 0; s < 1024; ++s) {
    const u16* hb  = hbuf + (size_t)(s & 1) * 65536;
    u16*       hbn = hbuf + (size_t)((s + 1) & 1) * 65536;

    // gi loads (HBM, streaming) + h fragment loads (fresh after last step's inv)
    size_t gib = ((size_t)(s * 64 + en)) * 3072 + gcol;
    float gir = bf2f(gi[gib]);
    float giz = bf2f(gi[gib + 1024]);
    float gin = bf2f(gi[gib + 2048]);

    const u16* hp = hb + aoff;
    bf16x8 af[8];
#pragma unroll
    for (int kk = 0; kk < 8; ++kk) af[kk] = *(const bf16x8*)(hp + kk * 32);

    f32x4 acc[3];
    acc[0] = (f32x4){0,0,0,0}; acc[1] = acc[0]; acc[2] = acc[0];
#pragma unroll
    for (int kk = 0; kk < 8; ++kk) {
      acc[0] = __builtin_amdgcn_mfma_f32_16x16x32_bf16(af[kk], wreg[0][kk], acc[0], 0, 0, 0);
      acc[1] = __builtin_amdgcn_mfma_f32_16x16x32_bf16(af[kk], wreg[1][kk], acc[1], 0, 0, 0);
      acc[2] = __builtin_amdgcn_mfma_f32_16x16x32_bf16(af[kk], wreg[2][kk], acc[2], 0, 0, 0);
    }
#pragma unroll
    for (int c = 0; c < 3; ++c) {
      float* pp = &part[((wv * 3 + c) * 16 + (lane & 15)) * 17 + (lane >> 4) * 4];
      pp[0] = acc[c][0]; pp[1] = acc[c][1]; pp[2] = acc[c][2]; pp[3] = acc[c][3];
    }
    __syncthreads();

    float ghr = 0.f, ghz = 0.f, ghn = 0.f;
#pragma unroll
    for (int ww = 0; ww < 4; ++ww) {
      ghr += part[((ww * 3 + 0) * 16 + ej) * 17 + erow];
      ghz += part[((ww * 3 + 1) * 16 + ej) * 17 + erow];
      ghn += part[((ww * 3 + 2) * 16 + ej) * 17 + erow];
    }
    float rg = sigmf(gir + bihr + ghr + bhhr);
    float zg = sigmf(giz + bihz + ghz + bhhz);
    float ng = tanhf_fast(gin + bihn + rg * (ghn + bhhn));
    float hn = (1.f - zg) * ng + zg * hcur;
    hcur = hn;

    // h broadcast: pack 2 cols -> u32, agent-scope relaxed store (write-through)
    u32 me = f2bf(hn);
    u32 nb = __shfl_down(me, 1);
    if (!(ej & 1))
      __hip_atomic_store((u32*)&hbn[en * 1024 + gcol], me | (nb << 16),
                         __ATOMIC_RELAXED, __HIP_MEMORY_SCOPE_AGENT);
    if (s == 1023) out[(size_t)67108864 + (size_t)en * 1024 + gcol] = hn;

    // ---- group barrier: no per-poll cache maintenance ----
    __syncthreads();   // all waves drained (vmcnt0) -> h stores at coherence point
    if (tid == 0) {
      __hip_atomic_fetch_add(cnt, 1u, __ATOMIC_RELAXED, __HIP_MEMORY_SCOPE_AGENT);
      const u32 tgt = 64u * (u32)(s + 1);
      while (__hip_atomic_load(cnt, __ATOMIC_RELAXED, __HIP_MEMORY_SCOPE_AGENT) < tgt)
        __builtin_amdgcn_s_sleep(1);
      __builtin_amdgcn_fence(__ATOMIC_ACQUIRE, "agent");  // one buffer_inv
    }
    __syncthreads();

    // out store issued post-barrier: HBM ack hides under next step's compute
    __builtin_nontemporal_store(hn, &out[(size_t)en * 1048576 + (size_t)s * 1024 + gcol]);
  }
}

// ---------------- launch ----------------
extern "C" void kernel_launch(void* const* d_in, const int* in_sizes, int n_in,
                              void* d_out, int out_size, void* d_ws, size_t ws_size,
                              hipStream_t stream) {
  const float* x     = (const float*)d_in[0];
  const float* h0    = (const float*)d_in[1];
  const float* wih_f = (const float*)d_in[2];
  const float* whh_f = (const float*)d_in[3];
  const float* bih   = (const float*)d_in[4];
  const float* bhh   = (const float*)d_in[5];
  float* out = (float*)d_out;

  if (ws_size < WS_END) return;

  char* ws = (char*)d_ws;
  u32* bar   = (u32*)(ws + WS_BAR);
  u16* hbuf  = (u16*)(ws + WS_HBUF);
  u16* wih_b = (u16*)(ws + WS_WIH);
  u16* whh_b = (u16*)(ws + WS_WHH);
  u16* gi    = (u16*)(ws + WS_GI);

  hipMemsetAsync(bar, 0, 4096, stream);

  cvt4_kernel<<<3072, 256, 0, stream>>>(wih_f, wih_b, 786432);
  cvt4_kernel<<<3072, 256, 0, stream>>>(whh_f, whh_b, 786432);
  cvt4_kernel<<<64,   256, 0, stream>>>(h0, hbuf, 16384);

  gemm_gi_kernel<<<12288, 256, 0, stream>>>(x, wih_b, gi);

  gru_scan_kernel<<<256, 256, 0, stream>>>(gi, whh_b, h0, bih, bhh, hbuf, bar, out);
}